// Round 7
// baseline (333.260 us; speedup 1.0000x reference)
//
#include <hip/hip_runtime.h>
#include <hip/hip_bf16.h>

// Problem constants
#define BB   2
#define SEQ  2048
#define DIMD 2048
#define NHH  32
#define NKVV 8
#define HDD  64
#define QKVS 3072
// N_REP = 4

typedef __bf16 bf16x8 __attribute__((ext_vector_type(8)));
typedef float  floatx4 __attribute__((ext_vector_type(4)));

typedef __attribute__((address_space(1))) const void* gas_ptr;
typedef __attribute__((address_space(3))) void*       las_ptr;

__device__ __forceinline__ unsigned short f2bu(float f) {
    __hip_bfloat16 h = __float2bfloat16(f);
    return *reinterpret_cast<unsigned short*>(&h);
}

// ---------------------------------------------------------------------------
// Fused f32 -> bf16 conversion for all 5 inputs + packed {cos,sin} float2
// table, one launch. Segment sizes in f32 elements.
// ---------------------------------------------------------------------------
#define C_X  (8u  * 1024 * 1024)
#define C_WQ (4u  * 1024 * 1024)
#define C_WK (1u  * 1024 * 1024)
#define C_WV (1u  * 1024 * 1024)
#define C_WO (4u  * 1024 * 1024)
#define C_CS (64u * 1024)          // 2048*32 cos/sin pairs
__global__ void cvt_all(const float* __restrict__ x,  const float* __restrict__ wq,
                        const float* __restrict__ wk, const float* __restrict__ wv,
                        const float* __restrict__ wo,
                        const float* __restrict__ rc, const float* __restrict__ rs,
                        __hip_bfloat16* __restrict__ xb,
                        __hip_bfloat16* __restrict__ wqkv,
                        __hip_bfloat16* __restrict__ wob,
                        float2* __restrict__ cs2)
{
    unsigned i = (blockIdx.x * blockDim.x + threadIdx.x) * 4;
    const unsigned e0 = C_X, e1 = e0 + C_WQ, e2 = e1 + C_WK, e3 = e2 + C_WV, e4 = e3 + C_WO;
    if (i >= e4) {
        unsigned o = i - e4;
        if (o >= C_CS) return;
        float4 c = *reinterpret_cast<const float4*>(rc + o);
        float4 s = *reinterpret_cast<const float4*>(rs + o);
        cs2[o + 0] = make_float2(c.x, s.x);
        cs2[o + 1] = make_float2(c.y, s.y);
        cs2[o + 2] = make_float2(c.z, s.z);
        cs2[o + 3] = make_float2(c.w, s.w);
        return;
    }
    const float* src; __hip_bfloat16* dst;
    if (i < e0)      { src = x  + i;          dst = xb + i; }
    else if (i < e1) { unsigned o = i - e0;   src = wq + o; dst = wqkv + o; }
    else if (i < e2) { unsigned o = i - e1;   src = wk + o; dst = wqkv + C_WQ + o; }
    else if (i < e3) { unsigned o = i - e2;   src = wv + o; dst = wqkv + C_WQ + C_WK + o; }
    else             { unsigned o = i - e3;   src = wo + o; dst = wob + o; }
    float4 v = *reinterpret_cast<const float4*>(src);
    dst[0] = __float2bfloat16(v.x);
    dst[1] = __float2bfloat16(v.y);
    dst[2] = __float2bfloat16(v.z);
    dst[3] = __float2bfloat16(v.w);
}

// ---------------------------------------------------------------------------
// GEMM (m97-style): C[M,ldc] = A[M,K] @ W[N,K]^T, bf16 in, f32 acc.
// ROPE=true: apply RoPE in the f32 epilogue for cols < 2560 (q|k sections),
// reading one packed float2 {cos,sin} per rotation pair (register-lean).
// ---------------------------------------------------------------------------
template <typename OutT, bool ROPE>
__global__ __launch_bounds__(256) void gemm_lds(
    const __hip_bfloat16* __restrict__ Abf,
    const __hip_bfloat16* __restrict__ Wbf,
    OutT* __restrict__ C,
    int M, int N, int K, int ldc,
    const float2* __restrict__ cs2)
{
    const __bf16* A = reinterpret_cast<const __bf16*>(Abf);
    const __bf16* W = reinterpret_cast<const __bf16*>(Wbf);

    __shared__ __bf16 As[128 * 32];   // 8 KB
    __shared__ __bf16 Bs[128 * 32];   // 8 KB

    int tid  = threadIdx.x;
    int wid  = tid >> 6;
    int lane = tid & 63;
    int l15  = lane & 15;
    int l4   = lane >> 4;
    int wm   = (wid & 1) * 64;
    int wn   = (wid >> 1) * 64;
    int bm   = blockIdx.x * 128;
    int bn   = blockIdx.y * 128;

    int r0 = tid >> 2,         g0 = (tid & 3) ^ ((r0 >> 1) & 3);
    int r1 = (tid + 256) >> 2, g1 = (tid & 3) ^ ((r1 >> 1) & 3);

    const __bf16* a0 = A + (size_t)(bm + r0) * K + g0 * 8;
    const __bf16* a1 = A + (size_t)(bm + r1) * K + g1 * 8;
    const __bf16* w0 = W + (size_t)(bn + r0) * K + g0 * 8;
    const __bf16* w1 = W + (size_t)(bn + r1) * K + g1 * 8;

    __bf16* lA0 = As + tid * 8;
    __bf16* lA1 = As + (tid + 256) * 8;
    __bf16* lB0 = Bs + tid * 8;
    __bf16* lB1 = Bs + (tid + 256) * 8;

    int arow[4], aslot[4], brow[4], bslot[4];
    #pragma unroll
    for (int i = 0; i < 4; ++i) {
        int ra = wm + i * 16 + l15;
        int rb = wn + i * 16 + l15;
        arow[i] = ra; aslot[i] = l4 ^ ((ra >> 1) & 3);
        brow[i] = rb; bslot[i] = l4 ^ ((rb >> 1) & 3);
    }

    floatx4 acc[4][4] = {};

    for (int k0 = 0; k0 < K; k0 += 32) {
        __builtin_amdgcn_global_load_lds((gas_ptr)(a0 + k0), (las_ptr)lA0, 16, 0, 0);
        __builtin_amdgcn_global_load_lds((gas_ptr)(a1 + k0), (las_ptr)lA1, 16, 0, 0);
        __builtin_amdgcn_global_load_lds((gas_ptr)(w0 + k0), (las_ptr)lB0, 16, 0, 0);
        __builtin_amdgcn_global_load_lds((gas_ptr)(w1 + k0), (las_ptr)lB1, 16, 0, 0);
        __syncthreads();

        bf16x8 af[4], bfr[4];
        #pragma unroll
        for (int i = 0; i < 4; ++i)
            af[i] = *reinterpret_cast<const bf16x8*>(As + arow[i] * 32 + aslot[i] * 8);
        #pragma unroll
        for (int j = 0; j < 4; ++j)
            bfr[j] = *reinterpret_cast<const bf16x8*>(Bs + brow[j] * 32 + bslot[j] * 8);

        #pragma unroll
        for (int i = 0; i < 4; ++i)
            #pragma unroll
            for (int j = 0; j < 4; ++j)
                acc[i][j] = __builtin_amdgcn_mfma_f32_16x16x32_bf16(af[i], bfr[j], acc[i][j], 0, 0, 0);
        __syncthreads();
    }

    if constexpr (ROPE) {
        bool do_rope = (bn + wn) < 2560;   // q|k sections; wave-uniform
        #pragma unroll
        for (int i = 0; i < 4; ++i) {
            #pragma unroll
            for (int r = 0; r < 4; ++r) {
                int row = bm + wm + i * 16 + l4 * 4 + r;
                int s   = row & (SEQ - 1);
                const float2* csrow = cs2 + s * 32 + l15;
                #pragma unroll
                for (int j = 0; j < 2; ++j) {
                    float x1 = acc[i][j][r], x2 = acc[i][j + 2][r];
                    if (do_rope) {
                        float2 cf = csrow[j * 16];
                        float o1 = x1 * cf.x - x2 * cf.y;
                        float o2 = x2 * cf.x + x1 * cf.y;
                        x1 = o1; x2 = o2;
                    }
                    int col = bn + wn + j * 16 + l15;
                    C[(size_t)row * ldc + col]      = __float2bfloat16(x1);
                    C[(size_t)row * ldc + col + 32] = __float2bfloat16(x2);
                }
            }
        }
    } else {
        #pragma unroll
        for (int i = 0; i < 4; ++i)
            #pragma unroll
            for (int j = 0; j < 4; ++j)
                #pragma unroll
                for (int r = 0; r < 4; ++r) {
                    int row = bm + wm + i * 16 + l4 * 4 + r;
                    int col = bn + wn + j * 16 + l15;
                    if constexpr (sizeof(OutT) == 4)
                        C[(size_t)row * ldc + col] = acc[i][j][r];
                    else
                        C[(size_t)row * ldc + col] = __float2bfloat16(acc[i][j][r]);
                }
    }
}

// ---------------------------------------------------------------------------
// V transpose: vT[b][kvh][d][s] <- qkv v-section [b*S+s][2560 + kvh*64 + d]
// ---------------------------------------------------------------------------
__global__ void transpose_v(const __hip_bfloat16* __restrict__ qkv,
                            unsigned short* __restrict__ vT)
{
    __shared__ unsigned short T[64][68];
    int s0  = blockIdx.x * 64;
    int kvh = blockIdx.y;
    int b   = blockIdx.z;
    int tid = threadIdx.x;

    int srow = tid >> 2, dg = (tid & 3) * 16;
    const unsigned short* src = reinterpret_cast<const unsigned short*>(qkv)
        + (size_t)(b * SEQ + s0 + srow) * QKVS + 2560 + kvh * 64 + dg;
    #pragma unroll
    for (int i = 0; i < 4; ++i)
        *reinterpret_cast<ushort4*>(&T[srow][dg + i * 4]) =
            *reinterpret_cast<const ushort4*>(src + i * 4);
    __syncthreads();

    int drow = tid >> 2, sg = (tid & 3) * 16;
    unsigned short* dst = vT + ((size_t)(b * NKVV + kvh) * 64 + drow) * SEQ + s0 + sg;
    #pragma unroll
    for (int i = 0; i < 4; ++i) {
        ushort4 u;
        u.x = T[sg + i * 4 + 0][drow];
        u.y = T[sg + i * 4 + 1][drow];
        u.z = T[sg + i * 4 + 2][drow];
        u.w = T[sg + i * 4 + 3][drow];
        *reinterpret_cast<ushort4*>(dst + i * 4) = u;
    }
}

// ---------------------------------------------------------------------------
// MFMA flash attention, doc+causal, doc-skip at chunk level.
// grid (S/128, NH, B) reversed; block 256 (4 waves), wave owns 32 queries.
// ---------------------------------------------------------------------------
__global__ __launch_bounds__(256) void attn_mfma(
    const __hip_bfloat16* __restrict__ qkv,  // [B*S][3072]: q | k | v
    const unsigned short* __restrict__ vT,   // [B][NKV][64][S]
    const int* __restrict__ doc,             // [B][S]
    __hip_bfloat16* __restrict__ ob)         // [B*S][NH*64]
{
    int qblk = (int)gridDim.x - 1 - (int)blockIdx.x;   // heavy blocks first
    int h    = blockIdx.y;
    int b    = blockIdx.z;
    int kvh  = h >> 2;
    int tid  = threadIdx.x;
    int wv   = tid >> 6;
    int lane = tid & 63;
    int l15  = lane & 15;
    int l4   = lane >> 4;
    int q0   = qblk * 128;
    int qw   = q0 + wv * 32;

    __shared__ unsigned short Ks[64 * 64];    // [key][dim], swizzled chunks
    __shared__ unsigned short Vts[64 * 64];   // [dim][key], swizzled chunks
    __shared__ unsigned short Pb[4][32][76];  // per-wave P tile
    __shared__ int kdoc[64];

    const unsigned short* qus = reinterpret_cast<const unsigned short*>(qkv);
    const unsigned short* kus = qus + 2048;

    bf16x8 aq[2][2];
    #pragma unroll
    for (int qt = 0; qt < 2; ++qt) {
        const unsigned short* qrow = qus + (size_t)(b * SEQ + qw + qt * 16 + l15) * QKVS + h * HDD;
        aq[qt][0] = *reinterpret_cast<const bf16x8*>(qrow + l4 * 8);
        aq[qt][1] = *reinterpret_cast<const bf16x8*>(qrow + 32 + l4 * 8);
    }
    int qd[2][4];
    #pragma unroll
    for (int qt = 0; qt < 2; ++qt)
        #pragma unroll
        for (int r = 0; r < 4; ++r)
            qd[qt][r] = doc[b * SEQ + qw + qt * 16 + l4 * 4 + r];
    int qd_w   = doc[b * SEQ + qw];
    int qd_blk = doc[b * SEQ + q0];

    float mrow[2][4], lrow[2][4];
    #pragma unroll
    for (int qt = 0; qt < 2; ++qt)
        #pragma unroll
        for (int r = 0; r < 4; ++r) { mrow[qt][r] = -1e30f; lrow[qt][r] = 0.f; }
    floatx4 accO[2][4] = {};

    int slot0 = tid, slot1 = tid + 256;
    int row0 = slot0 >> 3, g0 = (slot0 & 7) ^ (row0 & 7);
    int row1 = slot1 >> 3, g1 = (slot1 & 7) ^ (row1 & 7);
    const unsigned short* vtb = vT + ((size_t)(b * NKVV + kvh) * 64) * SEQ;

    int kc_end = 2 * qblk + 1;
    for (int kc = 0; kc <= kc_end; ++kc) {
        int k0 = kc * 64;
        int kd_last = doc[b * SEQ + k0 + 63];
        if (kd_last < qd_blk) continue;        // block-uniform doc skip

        __syncthreads();
        __builtin_amdgcn_global_load_lds(
            (gas_ptr)(kus + (size_t)(b * SEQ + k0 + row0) * QKVS + kvh * HDD + g0 * 8),
            (las_ptr)(Ks + slot0 * 8), 16, 0, 0);
        __builtin_amdgcn_global_load_lds(
            (gas_ptr)(kus + (size_t)(b * SEQ + k0 + row1) * QKVS + kvh * HDD + g1 * 8),
            (las_ptr)(Ks + slot1 * 8), 16, 0, 0);
        __builtin_amdgcn_global_load_lds(
            (gas_ptr)(vtb + (size_t)row0 * SEQ + k0 + g0 * 8),
            (las_ptr)(Vts + slot0 * 8), 16, 0, 0);
        __builtin_amdgcn_global_load_lds(
            (gas_ptr)(vtb + (size_t)row1 * SEQ + k0 + g1 * 8),
            (las_ptr)(Vts + slot1 * 8), 16, 0, 0);
        if (tid < 64) kdoc[tid] = doc[b * SEQ + k0 + tid];
        __syncthreads();

        if (k0 <= qw + 31 && kd_last >= qd_w) {   // wave-uniform compute skip
            #pragma unroll
            for (int qt = 0; qt < 2; ++qt) {
                float s[4][4];
                #pragma unroll
                for (int t = 0; t < 4; ++t) {
                    int krow = t * 16 + l15;
                    bf16x8 bk0 = *reinterpret_cast<const bf16x8*>(Ks + krow * 64 + ((l4 ^ (krow & 7)) * 8));
                    bf16x8 bk1 = *reinterpret_cast<const bf16x8*>(Ks + krow * 64 + ((((l4 + 4)) ^ (krow & 7)) * 8));
                    floatx4 acc = {};
                    acc = __builtin_amdgcn_mfma_f32_16x16x32_bf16(aq[qt][0], bk0, acc, 0, 0, 0);
                    acc = __builtin_amdgcn_mfma_f32_16x16x32_bf16(aq[qt][1], bk1, acc, 0, 0, 0);
                    int key = k0 + krow;
                    int kd  = kdoc[krow];
                    #pragma unroll
                    for (int r = 0; r < 4; ++r) {
                        int qrow = qw + qt * 16 + l4 * 4 + r;
                        bool valid = (kd == qd[qt][r]) && (key <= qrow);
                        s[t][r] = valid ? acc[r] * 0.125f : -1e30f;
                    }
                }
                #pragma unroll
                for (int r = 0; r < 4; ++r) {
                    float pm = fmaxf(fmaxf(s[0][r], s[1][r]), fmaxf(s[2][r], s[3][r]));
                    pm = fmaxf(pm, __shfl_xor(pm, 1));
                    pm = fmaxf(pm, __shfl_xor(pm, 2));
                    pm = fmaxf(pm, __shfl_xor(pm, 4));
                    pm = fmaxf(pm, __shfl_xor(pm, 8));
                    float mnew = fmaxf(mrow[qt][r], pm);
                    float alpha = __expf(mrow[qt][r] - mnew);
                    mrow[qt][r] = mnew;
                    float ps = 0.f;
                    #pragma unroll
                    for (int t = 0; t < 4; ++t) {
                        float p = (s[t][r] <= -1e29f) ? 0.f : __expf(s[t][r] - mnew);
                        Pb[wv][qt * 16 + l4 * 4 + r][t * 16 + l15] = f2bu(p);
                        ps += p;
                    }
                    ps += __shfl_xor(ps, 1);
                    ps += __shfl_xor(ps, 2);
                    ps += __shfl_xor(ps, 4);
                    ps += __shfl_xor(ps, 8);
                    lrow[qt][r] = lrow[qt][r] * alpha + ps;
                    #pragma unroll
                    for (int t = 0; t < 4; ++t) accO[qt][t][r] *= alpha;
                }
            }
            #pragma unroll
            for (int qt = 0; qt < 2; ++qt) {
                bf16x8 ap0 = *reinterpret_cast<const bf16x8*>(&Pb[wv][qt * 16 + l15][l4 * 8]);
                bf16x8 ap1 = *reinterpret_cast<const bf16x8*>(&Pb[wv][qt * 16 + l15][32 + l4 * 8]);
                #pragma unroll
                for (int t = 0; t < 4; ++t) {
                    int vrow = t * 16 + l15;
                    bf16x8 bv0 = *reinterpret_cast<const bf16x8*>(Vts + vrow * 64 + ((l4 ^ (vrow & 7)) * 8));
                    bf16x8 bv1 = *reinterpret_cast<const bf16x8*>(Vts + vrow * 64 + ((((l4 + 4)) ^ (vrow & 7)) * 8));
                    accO[qt][t] = __builtin_amdgcn_mfma_f32_16x16x32_bf16(ap0, bv0, accO[qt][t], 0, 0, 0);
                    accO[qt][t] = __builtin_amdgcn_mfma_f32_16x16x32_bf16(ap1, bv1, accO[qt][t], 0, 0, 0);
                }
            }
        }
    }

    #pragma unroll
    for (int qt = 0; qt < 2; ++qt)
        #pragma unroll
        for (int r = 0; r < 4; ++r) {
            float inv = 1.0f / lrow[qt][r];
            size_t base = (size_t)(b * SEQ + qw + qt * 16 + l4 * 4 + r) * (NHH * HDD) + h * HDD;
            #pragma unroll
            for (int t = 0; t < 4; ++t)
                ob[base + t * 16 + l15] = __float2bfloat16(accO[qt][t][r] * inv);
        }
}

// ---------------------------------------------------------------------------
extern "C" void kernel_launch(void* const* d_in, const int* in_sizes, int n_in,
                              void* d_out, int out_size, void* d_ws, size_t ws_size,
                              hipStream_t stream) {
    const float* x  = (const float*)d_in[0];
    const float* rc = (const float*)d_in[1];
    const float* rs = (const float*)d_in[2];
    const int*   dc = (const int*)d_in[3];
    const float* Wq = (const float*)d_in[4];
    const float* Wk = (const float*)d_in[5];
    const float* Wv = (const float*)d_in[6];
    const float* Wo = (const float*)d_in[7];
    float* out = (float*)d_out;

    const int M   = BB * SEQ;        // 4096
    const int KVD = NKVV * HDD;      // 512
    const int QKVN = DIMD + 2 * KVD; // 3072

    char* ws = (char*)d_ws;
    size_t off = 0;
    auto alloc = [&](size_t elems) { __hip_bfloat16* p = (__hip_bfloat16*)(ws + off); off += elems * 2; return p; };
    __hip_bfloat16* xb   = alloc((size_t)M * DIMD);      // 16 MB
    __hip_bfloat16* wqkv = alloc((size_t)QKVN * DIMD);   // 12 MB
    __hip_bfloat16* wob  = alloc((size_t)DIMD * DIMD);   //  8 MB
    __hip_bfloat16* qkv  = alloc((size_t)M * QKVN);      // 24 MB
    __hip_bfloat16* abuf = alloc((size_t)M * DIMD);      // 16 MB
    unsigned short* vtb  = (unsigned short*)alloc((size_t)BB * NKVV * HDD * SEQ); // 4 MB
    float2* cs2 = (float2*)(ws + off); off += (size_t)C_CS * sizeof(float2);      // 512 KB

    // one fused conversion launch (bf16 casts + packed cos/sin table)
    {
        unsigned total4 = (C_X + C_WQ + C_WK + C_WV + C_WO + C_CS) / 4;
        cvt_all<<<dim3((total4 + 255) / 256), 256, 0, stream>>>(
            x, Wq, Wk, Wv, Wo, rc, rs, xb, wqkv, wob, cs2);
    }

    // fused QKV projection with RoPE epilogue: [4096][3072]
    gemm_lds<__hip_bfloat16, true><<<dim3(M / 128, QKVN / 128), 256, 0, stream>>>(
        xb, wqkv, qkv, M, QKVN, DIMD, QKVN, cs2);

    // V transpose for PV B-fragments
    transpose_v<<<dim3(SEQ / 64, NKVV, BB), 256, 0, stream>>>(qkv, vtb);

    // attention (MFMA, doc-skip)
    attn_mfma<<<dim3(SEQ / 128, NHH, BB), 256, 0, stream>>>(qkv, vtb, dc, abuf);

    // output projection (f32 out)
    gemm_lds<float, false><<<dim3(M / 128, DIMD / 128), 256, 0, stream>>>(
        abuf, wob, out, M, DIMD, DIMD, DIMD, nullptr);
}

// Round 8
// 303.182 us; speedup vs baseline: 1.0992x; 1.0992x over previous
//
#include <hip/hip_runtime.h>
#include <hip/hip_bf16.h>

// Problem constants
#define BB   2
#define SEQ  2048
#define DIMD 2048
#define NHH  32
#define NKVV 8
#define HDD  64
#define QKVS 3072
// N_REP = 4

typedef __bf16 bf16x8 __attribute__((ext_vector_type(8)));
typedef float  floatx4 __attribute__((ext_vector_type(4)));

typedef __attribute__((address_space(1))) const void* gas_ptr;
typedef __attribute__((address_space(3))) void*       las_ptr;

__device__ __forceinline__ unsigned short f2bu(float f) {
    __hip_bfloat16 h = __float2bfloat16(f);
    return *reinterpret_cast<unsigned short*>(&h);
}

// ---------------------------------------------------------------------------
// Fused f32 -> bf16 conversion for all 5 inputs (one launch).
// ---------------------------------------------------------------------------
#define C_X  (8u  * 1024 * 1024)
#define C_WQ (4u  * 1024 * 1024)
#define C_WK (1u  * 1024 * 1024)
#define C_WV (1u  * 1024 * 1024)
#define C_WO (4u  * 1024 * 1024)
__global__ void cvt_all(const float* __restrict__ x,  const float* __restrict__ wq,
                        const float* __restrict__ wk, const float* __restrict__ wv,
                        const float* __restrict__ wo,
                        __hip_bfloat16* __restrict__ xb,
                        __hip_bfloat16* __restrict__ wqkv,
                        __hip_bfloat16* __restrict__ wob)
{
    unsigned i = (blockIdx.x * blockDim.x + threadIdx.x) * 4;
    const unsigned e0 = C_X, e1 = e0 + C_WQ, e2 = e1 + C_WK, e3 = e2 + C_WV, e4 = e3 + C_WO;
    if (i >= e4) return;
    const float* src; __hip_bfloat16* dst;
    if (i < e0)      { src = x  + i;          dst = xb + i; }
    else if (i < e1) { unsigned o = i - e0;   src = wq + o; dst = wqkv + o; }
    else if (i < e2) { unsigned o = i - e1;   src = wk + o; dst = wqkv + C_WQ + o; }
    else if (i < e3) { unsigned o = i - e2;   src = wv + o; dst = wqkv + C_WQ + C_WK + o; }
    else             { unsigned o = i - e3;   src = wo + o; dst = wob + o; }
    float4 v = *reinterpret_cast<const float4*>(src);
    dst[0] = __float2bfloat16(v.x);
    dst[1] = __float2bfloat16(v.y);
    dst[2] = __float2bfloat16(v.z);
    dst[3] = __float2bfloat16(v.w);
}

// ---------------------------------------------------------------------------
// GEMM (m97-style): C[M,ldc] = A[M,K] @ W[N,K]^T, bf16 in, f32 acc.
// NO fused epilogue: epilogue register mass costs resident blocks/CU and
// K-loop MfmaUtil (measured R4->R6: VGPR 72/84/88 -> 74/90/120 us).
// ---------------------------------------------------------------------------
template <typename OutT>
__global__ __launch_bounds__(256) void gemm_lds(
    const __hip_bfloat16* __restrict__ Abf,
    const __hip_bfloat16* __restrict__ Wbf,
    OutT* __restrict__ C,
    int M, int N, int K, int ldc)
{
    const __bf16* A = reinterpret_cast<const __bf16*>(Abf);
    const __bf16* W = reinterpret_cast<const __bf16*>(Wbf);

    __shared__ __bf16 As[128 * 32];   // 8 KB
    __shared__ __bf16 Bs[128 * 32];   // 8 KB

    int tid  = threadIdx.x;
    int wid  = tid >> 6;
    int lane = tid & 63;
    int l15  = lane & 15;
    int l4   = lane >> 4;
    int wm   = (wid & 1) * 64;
    int wn   = (wid >> 1) * 64;
    int bm   = blockIdx.x * 128;
    int bn   = blockIdx.y * 128;

    int r0 = tid >> 2,         g0 = (tid & 3) ^ ((r0 >> 1) & 3);
    int r1 = (tid + 256) >> 2, g1 = (tid & 3) ^ ((r1 >> 1) & 3);

    const __bf16* a0 = A + (size_t)(bm + r0) * K + g0 * 8;
    const __bf16* a1 = A + (size_t)(bm + r1) * K + g1 * 8;
    const __bf16* w0 = W + (size_t)(bn + r0) * K + g0 * 8;
    const __bf16* w1 = W + (size_t)(bn + r1) * K + g1 * 8;

    __bf16* lA0 = As + tid * 8;
    __bf16* lA1 = As + (tid + 256) * 8;
    __bf16* lB0 = Bs + tid * 8;
    __bf16* lB1 = Bs + (tid + 256) * 8;

    int arow[4], aslot[4], brow[4], bslot[4];
    #pragma unroll
    for (int i = 0; i < 4; ++i) {
        int ra = wm + i * 16 + l15;
        int rb = wn + i * 16 + l15;
        arow[i] = ra; aslot[i] = l4 ^ ((ra >> 1) & 3);
        brow[i] = rb; bslot[i] = l4 ^ ((rb >> 1) & 3);
    }

    floatx4 acc[4][4] = {};

    for (int k0 = 0; k0 < K; k0 += 32) {
        __builtin_amdgcn_global_load_lds((gas_ptr)(a0 + k0), (las_ptr)lA0, 16, 0, 0);
        __builtin_amdgcn_global_load_lds((gas_ptr)(a1 + k0), (las_ptr)lA1, 16, 0, 0);
        __builtin_amdgcn_global_load_lds((gas_ptr)(w0 + k0), (las_ptr)lB0, 16, 0, 0);
        __builtin_amdgcn_global_load_lds((gas_ptr)(w1 + k0), (las_ptr)lB1, 16, 0, 0);
        __syncthreads();

        bf16x8 af[4], bfr[4];
        #pragma unroll
        for (int i = 0; i < 4; ++i)
            af[i] = *reinterpret_cast<const bf16x8*>(As + arow[i] * 32 + aslot[i] * 8);
        #pragma unroll
        for (int j = 0; j < 4; ++j)
            bfr[j] = *reinterpret_cast<const bf16x8*>(Bs + brow[j] * 32 + bslot[j] * 8);

        #pragma unroll
        for (int i = 0; i < 4; ++i)
            #pragma unroll
            for (int j = 0; j < 4; ++j)
                acc[i][j] = __builtin_amdgcn_mfma_f32_16x16x32_bf16(af[i], bfr[j], acc[i][j], 0, 0, 0);
        __syncthreads();
    }

    #pragma unroll
    for (int i = 0; i < 4; ++i)
        #pragma unroll
        for (int j = 0; j < 4; ++j)
            #pragma unroll
            for (int r = 0; r < 4; ++r) {
                int row = bm + wm + i * 16 + l4 * 4 + r;
                int col = bn + wn + j * 16 + l15;
                if constexpr (sizeof(OutT) == 4)
                    C[(size_t)row * ldc + col] = acc[i][j][r];
                else
                    C[(size_t)row * ldc + col] = __float2bfloat16(acc[i][j][r]);
            }
}

// ---------------------------------------------------------------------------
// RoPE over q (32 heads, col 0) and k (8 heads, col 2048) in one launch.
// Slot h: 0..31 -> q head h; 32..39 -> k head h-32. pair (d, d+32).
// ---------------------------------------------------------------------------
__global__ void rope_all(__hip_bfloat16* qkv,
                         const float* __restrict__ cosb,
                         const float* __restrict__ sinb)
{
    int idx = blockIdx.x * blockDim.x + threadIdx.x;
    int total = (BB * SEQ) * 40 * 32;
    if (idx >= total) return;
    int d   = idx & 31;
    int h   = (idx >> 5) % 40;
    int row = idx / (40 * 32);
    int s   = row & (SEQ - 1);
    int col = (h < 32) ? (h * 64 + d) : (2048 + (h - 32) * 64 + d);
    size_t base = (size_t)row * QKVS + col;
    float x1 = __bfloat162float(qkv[base]);
    float x2 = __bfloat162float(qkv[base + 32]);
    float c  = cosb[s * 32 + d];
    float sn = sinb[s * 32 + d];
    qkv[base]      = __float2bfloat16(x1 * c - x2 * sn);
    qkv[base + 32] = __float2bfloat16(x2 * c + x1 * sn);
}

// ---------------------------------------------------------------------------
// V transpose: vT[b][kvh][d][s] <- qkv v-section [b*S+s][2560 + kvh*64 + d]
// ---------------------------------------------------------------------------
__global__ void transpose_v(const __hip_bfloat16* __restrict__ qkv,
                            unsigned short* __restrict__ vT)
{
    __shared__ unsigned short T[64][68];
    int s0  = blockIdx.x * 64;
    int kvh = blockIdx.y;
    int b   = blockIdx.z;
    int tid = threadIdx.x;

    int srow = tid >> 2, dg = (tid & 3) * 16;
    const unsigned short* src = reinterpret_cast<const unsigned short*>(qkv)
        + (size_t)(b * SEQ + s0 + srow) * QKVS + 2560 + kvh * 64 + dg;
    #pragma unroll
    for (int i = 0; i < 4; ++i)
        *reinterpret_cast<ushort4*>(&T[srow][dg + i * 4]) =
            *reinterpret_cast<const ushort4*>(src + i * 4);
    __syncthreads();

    int drow = tid >> 2, sg = (tid & 3) * 16;
    unsigned short* dst = vT + ((size_t)(b * NKVV + kvh) * 64 + drow) * SEQ + s0 + sg;
    #pragma unroll
    for (int i = 0; i < 4; ++i) {
        ushort4 u;
        u.x = T[sg + i * 4 + 0][drow];
        u.y = T[sg + i * 4 + 1][drow];
        u.z = T[sg + i * 4 + 2][drow];
        u.w = T[sg + i * 4 + 3][drow];
        *reinterpret_cast<ushort4*>(dst + i * 4) = u;
    }
}

// ---------------------------------------------------------------------------
// MFMA flash attention, doc+causal, doc-skip at chunk level.
// grid (S/128, NH, B) reversed; block 256 (4 waves), wave owns 32 queries.
// ---------------------------------------------------------------------------
__global__ __launch_bounds__(256) void attn_mfma(
    const __hip_bfloat16* __restrict__ qkv,  // [B*S][3072]: q | k | v
    const unsigned short* __restrict__ vT,   // [B][NKV][64][S]
    const int* __restrict__ doc,             // [B][S]
    __hip_bfloat16* __restrict__ ob)         // [B*S][NH*64]
{
    int qblk = (int)gridDim.x - 1 - (int)blockIdx.x;   // heavy blocks first
    int h    = blockIdx.y;
    int b    = blockIdx.z;
    int kvh  = h >> 2;
    int tid  = threadIdx.x;
    int wv   = tid >> 6;
    int lane = tid & 63;
    int l15  = lane & 15;
    int l4   = lane >> 4;
    int q0   = qblk * 128;
    int qw   = q0 + wv * 32;

    __shared__ unsigned short Ks[64 * 64];    // [key][dim], swizzled chunks
    __shared__ unsigned short Vts[64 * 64];   // [dim][key], swizzled chunks
    __shared__ unsigned short Pb[4][32][76];  // per-wave P tile
    __shared__ int kdoc[64];

    const unsigned short* qus = reinterpret_cast<const unsigned short*>(qkv);
    const unsigned short* kus = qus + 2048;

    bf16x8 aq[2][2];
    #pragma unroll
    for (int qt = 0; qt < 2; ++qt) {
        const unsigned short* qrow = qus + (size_t)(b * SEQ + qw + qt * 16 + l15) * QKVS + h * HDD;
        aq[qt][0] = *reinterpret_cast<const bf16x8*>(qrow + l4 * 8);
        aq[qt][1] = *reinterpret_cast<const bf16x8*>(qrow + 32 + l4 * 8);
    }
    int qd[2][4];
    #pragma unroll
    for (int qt = 0; qt < 2; ++qt)
        #pragma unroll
        for (int r = 0; r < 4; ++r)
            qd[qt][r] = doc[b * SEQ + qw + qt * 16 + l4 * 4 + r];
    int qd_w   = doc[b * SEQ + qw];
    int qd_blk = doc[b * SEQ + q0];

    float mrow[2][4], lrow[2][4];
    #pragma unroll
    for (int qt = 0; qt < 2; ++qt)
        #pragma unroll
        for (int r = 0; r < 4; ++r) { mrow[qt][r] = -1e30f; lrow[qt][r] = 0.f; }
    floatx4 accO[2][4] = {};

    int slot0 = tid, slot1 = tid + 256;
    int row0 = slot0 >> 3, g0 = (slot0 & 7) ^ (row0 & 7);
    int row1 = slot1 >> 3, g1 = (slot1 & 7) ^ (row1 & 7);
    const unsigned short* vtb = vT + ((size_t)(b * NKVV + kvh) * 64) * SEQ;

    int kc_end = 2 * qblk + 1;
    for (int kc = 0; kc <= kc_end; ++kc) {
        int k0 = kc * 64;
        int kd_last = doc[b * SEQ + k0 + 63];
        if (kd_last < qd_blk) continue;        // block-uniform doc skip

        __syncthreads();
        __builtin_amdgcn_global_load_lds(
            (gas_ptr)(kus + (size_t)(b * SEQ + k0 + row0) * QKVS + kvh * HDD + g0 * 8),
            (las_ptr)(Ks + slot0 * 8), 16, 0, 0);
        __builtin_amdgcn_global_load_lds(
            (gas_ptr)(kus + (size_t)(b * SEQ + k0 + row1) * QKVS + kvh * HDD + g1 * 8),
            (las_ptr)(Ks + slot1 * 8), 16, 0, 0);
        __builtin_amdgcn_global_load_lds(
            (gas_ptr)(vtb + (size_t)row0 * SEQ + k0 + g0 * 8),
            (las_ptr)(Vts + slot0 * 8), 16, 0, 0);
        __builtin_amdgcn_global_load_lds(
            (gas_ptr)(vtb + (size_t)row1 * SEQ + k0 + g1 * 8),
            (las_ptr)(Vts + slot1 * 8), 16, 0, 0);
        if (tid < 64) kdoc[tid] = doc[b * SEQ + k0 + tid];
        __syncthreads();

        if (k0 <= qw + 31 && kd_last >= qd_w) {   // wave-uniform compute skip
            #pragma unroll
            for (int qt = 0; qt < 2; ++qt) {
                float s[4][4];
                #pragma unroll
                for (int t = 0; t < 4; ++t) {
                    int krow = t * 16 + l15;
                    bf16x8 bk0 = *reinterpret_cast<const bf16x8*>(Ks + krow * 64 + ((l4 ^ (krow & 7)) * 8));
                    bf16x8 bk1 = *reinterpret_cast<const bf16x8*>(Ks + krow * 64 + ((((l4 + 4)) ^ (krow & 7)) * 8));
                    floatx4 acc = {};
                    acc = __builtin_amdgcn_mfma_f32_16x16x32_bf16(aq[qt][0], bk0, acc, 0, 0, 0);
                    acc = __builtin_amdgcn_mfma_f32_16x16x32_bf16(aq[qt][1], bk1, acc, 0, 0, 0);
                    int key = k0 + krow;
                    int kd  = kdoc[krow];
                    #pragma unroll
                    for (int r = 0; r < 4; ++r) {
                        int qrow = qw + qt * 16 + l4 * 4 + r;
                        bool valid = (kd == qd[qt][r]) && (key <= qrow);
                        s[t][r] = valid ? acc[r] * 0.125f : -1e30f;
                    }
                }
                #pragma unroll
                for (int r = 0; r < 4; ++r) {
                    float pm = fmaxf(fmaxf(s[0][r], s[1][r]), fmaxf(s[2][r], s[3][r]));
                    pm = fmaxf(pm, __shfl_xor(pm, 1));
                    pm = fmaxf(pm, __shfl_xor(pm, 2));
                    pm = fmaxf(pm, __shfl_xor(pm, 4));
                    pm = fmaxf(pm, __shfl_xor(pm, 8));
                    float mnew = fmaxf(mrow[qt][r], pm);
                    float alpha = __expf(mrow[qt][r] - mnew);
                    mrow[qt][r] = mnew;
                    float ps = 0.f;
                    #pragma unroll
                    for (int t = 0; t < 4; ++t) {
                        float p = (s[t][r] <= -1e29f) ? 0.f : __expf(s[t][r] - mnew);
                        Pb[wv][qt * 16 + l4 * 4 + r][t * 16 + l15] = f2bu(p);
                        ps += p;
                    }
                    ps += __shfl_xor(ps, 1);
                    ps += __shfl_xor(ps, 2);
                    ps += __shfl_xor(ps, 4);
                    ps += __shfl_xor(ps, 8);
                    lrow[qt][r] = lrow[qt][r] * alpha + ps;
                    #pragma unroll
                    for (int t = 0; t < 4; ++t) accO[qt][t][r] *= alpha;
                }
            }
            #pragma unroll
            for (int qt = 0; qt < 2; ++qt) {
                bf16x8 ap0 = *reinterpret_cast<const bf16x8*>(&Pb[wv][qt * 16 + l15][l4 * 8]);
                bf16x8 ap1 = *reinterpret_cast<const bf16x8*>(&Pb[wv][qt * 16 + l15][32 + l4 * 8]);
                #pragma unroll
                for (int t = 0; t < 4; ++t) {
                    int vrow = t * 16 + l15;
                    bf16x8 bv0 = *reinterpret_cast<const bf16x8*>(Vts + vrow * 64 + ((l4 ^ (vrow & 7)) * 8));
                    bf16x8 bv1 = *reinterpret_cast<const bf16x8*>(Vts + vrow * 64 + ((((l4 + 4)) ^ (vrow & 7)) * 8));
                    accO[qt][t] = __builtin_amdgcn_mfma_f32_16x16x32_bf16(ap0, bv0, accO[qt][t], 0, 0, 0);
                    accO[qt][t] = __builtin_amdgcn_mfma_f32_16x16x32_bf16(ap1, bv1, accO[qt][t], 0, 0, 0);
                }
            }
        }
    }

    #pragma unroll
    for (int qt = 0; qt < 2; ++qt)
        #pragma unroll
        for (int r = 0; r < 4; ++r) {
            float inv = 1.0f / lrow[qt][r];
            size_t base = (size_t)(b * SEQ + qw + qt * 16 + l4 * 4 + r) * (NHH * HDD) + h * HDD;
            #pragma unroll
            for (int t = 0; t < 4; ++t)
                ob[base + t * 16 + l15] = __float2bfloat16(accO[qt][t][r] * inv);
        }
}

// ---------------------------------------------------------------------------
extern "C" void kernel_launch(void* const* d_in, const int* in_sizes, int n_in,
                              void* d_out, int out_size, void* d_ws, size_t ws_size,
                              hipStream_t stream) {
    const float* x  = (const float*)d_in[0];
    const float* rc = (const float*)d_in[1];
    const float* rs = (const float*)d_in[2];
    const int*   dc = (const int*)d_in[3];
    const float* Wq = (const float*)d_in[4];
    const float* Wk = (const float*)d_in[5];
    const float* Wv = (const float*)d_in[6];
    const float* Wo = (const float*)d_in[7];
    float* out = (float*)d_out;

    const int M   = BB * SEQ;        // 4096
    const int KVD = NKVV * HDD;      // 512
    const int QKVN = DIMD + 2 * KVD; // 3072

    char* ws = (char*)d_ws;
    size_t off = 0;
    auto alloc = [&](size_t elems) { __hip_bfloat16* p = (__hip_bfloat16*)(ws + off); off += elems * 2; return p; };
    __hip_bfloat16* xb   = alloc((size_t)M * DIMD);      // 16 MB
    __hip_bfloat16* wqkv = alloc((size_t)QKVN * DIMD);   // 12 MB
    __hip_bfloat16* wob  = alloc((size_t)DIMD * DIMD);   //  8 MB
    __hip_bfloat16* qkv  = alloc((size_t)M * QKVN);      // 24 MB
    __hip_bfloat16* abuf = alloc((size_t)M * DIMD);      // 16 MB
    unsigned short* vtb  = (unsigned short*)alloc((size_t)BB * NKVV * HDD * SEQ); // 4 MB

    // one fused f32->bf16 conversion launch
    {
        unsigned total4 = (C_X + C_WQ + C_WK + C_WV + C_WO) / 4;
        cvt_all<<<dim3((total4 + 255) / 256), 256, 0, stream>>>(
            x, Wq, Wk, Wv, Wo, xb, wqkv, wob);
    }

    // fused QKV projection: [4096][3072]
    gemm_lds<__hip_bfloat16><<<dim3(M / 128, QKVN / 128), 256, 0, stream>>>(
        xb, wqkv, qkv, M, QKVN, DIMD, QKVN);

    // RoPE on q and k sections (one launch)
    {
        int tot = M * 40 * 32;
        rope_all<<<(tot + 255) / 256, 256, 0, stream>>>(qkv, rc, rs);
    }

    // V transpose for PV B-fragments
    transpose_v<<<dim3(SEQ / 64, NKVV, BB), 256, 0, stream>>>(qkv, vtb);

    // attention (MFMA, doc-skip)
    attn_mfma<<<dim3(SEQ / 128, NHH, BB), 256, 0, stream>>>(qkv, vtb, dc, abuf);

    // output projection (f32 out)
    gemm_lds<float><<<dim3(M / 128, DIMD / 128), 256, 0, stream>>>(
        abuf, wob, out, M, DIMD, DIMD, DIMD);
}